// Round 13
// baseline (89.413 us; speedup 1.0000x reference)
//
#include <hip/hip_runtime.h>
#include <hip/hip_fp16.h>
#include <cstdint>
#include <cstddef>

#define BATCH 8
#define NPTS  2048
#define CH1   64
#define CH2   128
#define NSAMP 64

typedef _Float16 half8v  __attribute__((ext_vector_type(8)));
typedef _Float16 half2v  __attribute__((ext_vector_type(2)));
typedef float    float4v __attribute__((ext_vector_type(4)));
typedef unsigned uint4v  __attribute__((ext_vector_type(4)));

__device__ inline unsigned pmax(unsigned a, unsigned b) {
  half2v ha = __builtin_bit_cast(half2v, a);
  half2v hb = __builtin_bit_cast(half2v, b);
  return __builtin_bit_cast(unsigned, __builtin_elementwise_max(ha, hb));
}

__device__ inline uint4v pk4max(uint4v a, uint4v b) {
  uint4v d;
#pragma unroll
  for (int i = 0; i < 4; ++i) d[i] = pmax(a[i], b[i]);
  return d;
}

__device__ inline float h2lo(unsigned u) {
  return (float)__builtin_bit_cast(half2v, u)[0];
}
__device__ inline float h2hi(unsigned u) {
  return (float)__builtin_bit_cast(half2v, u)[1];
}

// ---------------------------------------------------------------------------
// Kernel 1: per-point MLP via MFMA (128 x 16384 x 64 fp16 GEMM). Unchanged
// from R7-R12 (measured fast). Also emits xyzq[pt] = {x,y,z,|p|^2}.
// ---------------------------------------------------------------------------
__global__ __launch_bounds__(256) void mlp_kernel(
    const float* __restrict__ x,
    const float* __restrict__ W1, const float* __restrict__ b1,
    const float* __restrict__ W2, const float* __restrict__ b2,
    __half* __restrict__ h2, float4v* __restrict__ xyzq) {
  const int t = threadIdx.x;
  const int wave = t >> 6;
  const int lane = t & 63;
  const int n = lane & 15;
  const int quad = lane >> 4;
  const int pti = wave >> 1;
  const int mh  = wave & 1;
  const int base = blockIdx.x * 32;

  if (t < 32) {
    const int pt = base + t;
    const float X = x[pt * 3 + 0];
    const float Y = x[pt * 3 + 1];
    const float Z = x[pt * 3 + 2];
    float4v v;
    v[0] = X; v[1] = Y; v[2] = Z; v[3] = fmaf(Z, Z, fmaf(Y, Y, X * X));
    xyzq[pt] = v;
  }

  float w1x[16], w1y[16], w1z[16], b1v[16];
#pragma unroll
  for (int j = 0; j < 16; ++j) {
    const int o = quad * 8 + (j & 7) + ((j < 8) ? 0 : 32);
    w1x[j] = W1[o * 3 + 0];
    w1y[j] = W1[o * 3 + 1];
    w1z[j] = W1[o * 3 + 2];
    b1v[j] = b1[o];
  }

  half8v afrag[4][2];
  float4v bias[4];
#pragma unroll
  for (int mt = 0; mt < 4; ++mt) {
    const int mtg = mh * 4 + mt;
    const int m = mtg * 16 + n;
#pragma unroll
    for (int kf = 0; kf < 2; ++kf) {
      const float4v* wp = (const float4v*)(W2 + m * CH1 + kf * 32 + quad * 8);
      const float4v lo = wp[0];
      const float4v hi = wp[1];
#pragma unroll
      for (int e = 0; e < 4; ++e) {
        afrag[mt][kf][e]     = (_Float16)lo[e];
        afrag[mt][kf][4 + e] = (_Float16)hi[e];
      }
    }
    bias[mt] = *(const float4v*)(b2 + mtg * 16 + quad * 4);
  }

  const int pt = base + pti * 16 + n;
  const float X = x[pt * 3 + 0];
  const float Y = x[pt * 3 + 1];
  const float Z = x[pt * 3 + 2];
  half8v bf0, bf1;
#pragma unroll
  for (int j = 0; j < 8; ++j) {
    const float ha = fmaxf(fmaf(w1z[j], Z, fmaf(w1y[j], Y, fmaf(w1x[j], X, b1v[j]))), 0.f);
    const float hb = fmaxf(fmaf(w1z[8 + j], Z, fmaf(w1y[8 + j], Y, fmaf(w1x[8 + j], X, b1v[8 + j]))), 0.f);
    bf0[j] = (_Float16)ha;
    bf1[j] = (_Float16)hb;
  }

  __half* hrow = h2 + (size_t)pt * CH2;
#pragma unroll
  for (int mt = 0; mt < 4; ++mt) {
    const int mtg = mh * 4 + mt;
    float4v acc = bias[mt];
    acc = __builtin_amdgcn_mfma_f32_16x16x32_f16(afrag[mt][0], bf0, acc, 0, 0, 0);
    acc = __builtin_amdgcn_mfma_f32_16x16x32_f16(afrag[mt][1], bf1, acc, 0, 0, 0);
    const int p0 = mtg * 16 + quad * 4;
    half2v lo2, hi2;
    lo2[0] = (_Float16)fmaxf(acc[0], 0.f);
    lo2[1] = (_Float16)fmaxf(acc[1], 0.f);
    hi2[0] = (_Float16)fmaxf(acc[2], 0.f);
    hi2[1] = (_Float16)fmaxf(acc[3], 0.f);
    uint2 pk;
    pk.x = __builtin_bit_cast(unsigned, lo2);
    pk.y = __builtin_bit_cast(unsigned, hi2);
    *(uint2*)(hrow + p0) = pk;
  }
}

// ---------------------------------------------------------------------------
// Kernel 2: one block (4 waves) per query, XCD-swizzled (R12). R13 cuts the
// common-path critical chain:
//  - phase 1 does candidates 0..511 UNCONDITIONALLY: both 16-B loads issued
//    up front, both ballots share ONE barrier (covers ~97% of queries; the
//    rare count<64 case falls into the old loop -- block-uniform branch).
//  - no pad pass: phase 2 clamps its list index to 0 when beyond count
//    (duplicate of row 0 is max-pool-neutral; self-hit guarantees list[0]).
// Common-path barriers: 5 -> 3.
// ---------------------------------------------------------------------------
__global__ __launch_bounds__(256) void query_kernel(
    const float4v* __restrict__ xyzq,
    const __half* __restrict__ h2,
    float* __restrict__ out) {
  __shared__ int list[NSAMP];
  __shared__ unsigned cnt[2][4];
  __shared__ uint4v partial[256];   // 4 KB

  const int t = threadIdx.x;
  const int wave = t >> 6;
  const int lane = t & 63;
  const int bid = blockIdx.x;
  const int q = ((bid & 7) << 11) | (bid >> 3);   // XCD-aware swizzle
  const int b = q >> 11;                          // == bid & 7 == XCD id
  const int s = q & (NPTS - 1);

  const float4v* xq = xyzq + (size_t)b * NPTS;
  const float4v qv = xq[s];
  const float qx = qv[0], qy = qv[1], qz = qv[2], dqf = qv[3];
  const double dq = (double)qx * qx + (double)qy * qy + (double)qz * qz;
  const unsigned long long lt = (1ull << lane) - 1ull;

  // ---- Phase 1a: candidates 0..511, both loads up front, one barrier ----
  const int m0 = wave * 64 + lane;
  const int m1 = 256 + m0;
  const float4v pv0 = xq[m0];
  const float4v pv1 = xq[m1];

  bool hit0, hit1;
  {
    const float px = pv0[0], py = pv0[1], pz = pv0[2];
    const float dot = fmaf(qz, pz, fmaf(qy, py, qx * px));
    const float dist = fmaf(-2.f, dot, dqf + pv0[3]);
    if (__ballot(__builtin_fabsf(dist - 0.36f) <= 3e-5f)) {
      const double dm = (double)px * px + (double)py * py + (double)pz * pz;
      const double dd = (double)qx * px + (double)qy * py + (double)qz * pz;
      hit0 = !((dq + dm - 2.0 * dd) > 0.36);
    } else {
      hit0 = !(dist > 0.36f);
    }
  }
  {
    const float px = pv1[0], py = pv1[1], pz = pv1[2];
    const float dot = fmaf(qz, pz, fmaf(qy, py, qx * px));
    const float dist = fmaf(-2.f, dot, dqf + pv1[3]);
    if (__ballot(__builtin_fabsf(dist - 0.36f) <= 3e-5f)) {
      const double dm = (double)px * px + (double)py * py + (double)pz * pz;
      const double dd = (double)qx * px + (double)qy * py + (double)qz * pz;
      hit1 = !((dq + dm - 2.0 * dd) > 0.36);
    } else {
      hit1 = !(dist > 0.36f);
    }
  }
  const unsigned long long k0 = __ballot(hit0);
  const unsigned long long k1 = __ballot(hit1);
  if (lane == 0) {
    cnt[0][wave] = (unsigned)__popcll(k0);
    cnt[1][wave] = (unsigned)__popcll(k1);
  }
  __syncthreads();

  int pre0 = 0, tot0 = 0, pre1 = 0, tot1 = 0;
#pragma unroll
  for (int w = 0; w < 4; ++w) {
    const int c0 = (int)cnt[0][w];
    const int c1 = (int)cnt[1][w];
    if (w < wave) { pre0 += c0; pre1 += c1; }
    tot0 += c0;
    tot1 += c1;
  }
  pre1 += tot0;
  if (hit0) {
    const int pos = pre0 + __popcll(k0 & lt);
    if (pos < NSAMP) list[pos] = m0;
  }
  if (hit1) {
    const int pos = pre1 + __popcll(k1 & lt);
    if (pos < NSAMP) list[pos] = m1;
  }
  int count = tot0 + tot1;

  // ---- Phase 1b: rare path (near-corner queries), block-uniform branch ----
  if (count < NSAMP) {
    __syncthreads();   // protect cnt slots before reuse
    int it = 0;
    for (int base2 = 512; base2 < NPTS && count < NSAMP; base2 += 256, ++it) {
      const int m = base2 + wave * 64 + lane;
      const float4v pv = xq[m];
      const float px = pv[0], py = pv[1], pz = pv[2];
      const float dot = fmaf(qz, pz, fmaf(qy, py, qx * px));
      const float dist = fmaf(-2.f, dot, dqf + pv[3]);
      bool hit;
      if (__ballot(__builtin_fabsf(dist - 0.36f) <= 3e-5f)) {
        const double dm = (double)px * px + (double)py * py + (double)pz * pz;
        const double dd = (double)qx * px + (double)qy * py + (double)qz * pz;
        hit = !((dq + dm - 2.0 * dd) > 0.36);
      } else {
        hit = !(dist > 0.36f);
      }
      const unsigned long long mask = __ballot(hit);
      const int par = it & 1;
      if (lane == 0) cnt[par][wave] = (unsigned)__popcll(mask);
      __syncthreads();
      int pre = count;
#pragma unroll
      for (int w = 0; w < 3; ++w)
        if (wave > w) pre += (int)cnt[par][w];
      if (hit) {
        const int pos = pre + __popcll(mask & lt);
        if (pos < NSAMP) list[pos] = m;
      }
      count += (int)(cnt[par][0] + cnt[par][1] + cnt[par][2] + cnt[par][3]);
    }
  }
  __syncthreads();   // list visible to phase 2

  // ---- Phase 2: coalesced gather, index clamped to 0 beyond count ----
  const int rowsel = t >> 4;   // 0..15
  const int csl = t & 15;      // 16-B channel slice
  const unsigned long long hb =
      (unsigned long long)(h2 + (size_t)b * NPTS * CH2) + (unsigned)(csl * 16);

  unsigned long long ad[4];
#pragma unroll
  for (int r = 0; r < 4; ++r) {
    const int ri = r * 16 + rowsel;
    const int li = (ri < count) ? ri : 0;   // dup of row 0 is max-neutral
    ad[r] = hb + (unsigned)(list[li] * 256);
  }

  uint4v v0, v1, v2, v3;
  asm volatile(
      "global_load_dwordx4 %0, %4, off\n\t"
      "global_load_dwordx4 %1, %5, off\n\t"
      "global_load_dwordx4 %2, %6, off\n\t"
      "global_load_dwordx4 %3, %7, off\n\t"
      "s_waitcnt vmcnt(0)"
      : "=&v"(v0), "=&v"(v1), "=&v"(v2), "=&v"(v3)
      : "v"(ad[0]), "v"(ad[1]), "v"(ad[2]), "v"(ad[3])
      : "memory");

  partial[t] = pk4max(pk4max(v0, v1), pk4max(v2, v3));
  __syncthreads();

  // ---- Final reduction: 64 threads, one dword (2 channels) each ----
  if (t < 64) {
    const int cs = t >> 2;      // 16-B slice (0..15)
    const int d  = t & 3;       // dword within slice
    const unsigned* pl = (const unsigned*)&partial[0];
    unsigned m = 0;
#pragma unroll
    for (int rs = 0; rs < 16; ++rs)
      m = pmax(m, pl[(rs * 16 + cs) * 4 + d]);
    const size_t ob = (size_t)b * CH2 * NPTS;
    out[ob + (size_t)(2 * t) * NPTS + s]     = h2lo(m);
    out[ob + (size_t)(2 * t + 1) * NPTS + s] = h2hi(m);
  }
}

// ---------------------------------------------------------------------------
extern "C" void kernel_launch(void* const* d_in, const int* in_sizes, int n_in,
                              void* d_out, int out_size, void* d_ws, size_t ws_size,
                              hipStream_t stream) {
  const float* x  = (const float*)d_in[0];
  const float* W1 = (const float*)d_in[1];
  const float* b1 = (const float*)d_in[2];
  const float* W2 = (const float*)d_in[3];
  const float* b2 = (const float*)d_in[4];
  float* out = (float*)d_out;

  __half*  h2   = (__half*)d_ws;                                     // 4 MB
  float4v* xyzq = (float4v*)((char*)d_ws + (size_t)4 * 1024 * 1024); // 256 KB

  mlp_kernel<<<(BATCH * NPTS) / 32, 256, 0, stream>>>(
      x, W1, b1, W2, b2, h2, xyzq);
  query_kernel<<<BATCH * NPTS, 256, 0, stream>>>(xyzq, h2, out);
}

// Round 14
// 88.420 us; speedup vs baseline: 1.0112x; 1.0112x over previous
//
#include <hip/hip_runtime.h>
#include <hip/hip_fp16.h>
#include <cstdint>
#include <cstddef>

#define BATCH 8
#define NPTS  2048
#define CH1   64
#define CH2   128
#define NSAMP 64

typedef _Float16 half8v  __attribute__((ext_vector_type(8)));
typedef _Float16 half2v  __attribute__((ext_vector_type(2)));
typedef float    float4v __attribute__((ext_vector_type(4)));
typedef unsigned uint4v  __attribute__((ext_vector_type(4)));

__device__ inline unsigned pmax(unsigned a, unsigned b) {
  half2v ha = __builtin_bit_cast(half2v, a);
  half2v hb = __builtin_bit_cast(half2v, b);
  return __builtin_bit_cast(unsigned, __builtin_elementwise_max(ha, hb));
}

__device__ inline uint4v pk4max(uint4v a, uint4v b) {
  uint4v d;
#pragma unroll
  for (int i = 0; i < 4; ++i) d[i] = pmax(a[i], b[i]);
  return d;
}

__device__ inline float h2lo(unsigned u) {
  return (float)__builtin_bit_cast(half2v, u)[0];
}
__device__ inline float h2hi(unsigned u) {
  return (float)__builtin_bit_cast(half2v, u)[1];
}

// ---------------------------------------------------------------------------
// Kernel 1: per-point MLP via MFMA (128 x 16384 x 64 fp16 GEMM). Unchanged
// from R7-R13 (measured fast). Also emits xyzq[pt] = {x,y,z,|p|^2}.
// ---------------------------------------------------------------------------
__global__ __launch_bounds__(256) void mlp_kernel(
    const float* __restrict__ x,
    const float* __restrict__ W1, const float* __restrict__ b1,
    const float* __restrict__ W2, const float* __restrict__ b2,
    __half* __restrict__ h2, float4v* __restrict__ xyzq) {
  const int t = threadIdx.x;
  const int wave = t >> 6;
  const int lane = t & 63;
  const int n = lane & 15;
  const int quad = lane >> 4;
  const int pti = wave >> 1;
  const int mh  = wave & 1;
  const int base = blockIdx.x * 32;

  if (t < 32) {
    const int pt = base + t;
    const float X = x[pt * 3 + 0];
    const float Y = x[pt * 3 + 1];
    const float Z = x[pt * 3 + 2];
    float4v v;
    v[0] = X; v[1] = Y; v[2] = Z; v[3] = fmaf(Z, Z, fmaf(Y, Y, X * X));
    xyzq[pt] = v;
  }

  float w1x[16], w1y[16], w1z[16], b1v[16];
#pragma unroll
  for (int j = 0; j < 16; ++j) {
    const int o = quad * 8 + (j & 7) + ((j < 8) ? 0 : 32);
    w1x[j] = W1[o * 3 + 0];
    w1y[j] = W1[o * 3 + 1];
    w1z[j] = W1[o * 3 + 2];
    b1v[j] = b1[o];
  }

  half8v afrag[4][2];
  float4v bias[4];
#pragma unroll
  for (int mt = 0; mt < 4; ++mt) {
    const int mtg = mh * 4 + mt;
    const int m = mtg * 16 + n;
#pragma unroll
    for (int kf = 0; kf < 2; ++kf) {
      const float4v* wp = (const float4v*)(W2 + m * CH1 + kf * 32 + quad * 8);
      const float4v lo = wp[0];
      const float4v hi = wp[1];
#pragma unroll
      for (int e = 0; e < 4; ++e) {
        afrag[mt][kf][e]     = (_Float16)lo[e];
        afrag[mt][kf][4 + e] = (_Float16)hi[e];
      }
    }
    bias[mt] = *(const float4v*)(b2 + mtg * 16 + quad * 4);
  }

  const int pt = base + pti * 16 + n;
  const float X = x[pt * 3 + 0];
  const float Y = x[pt * 3 + 1];
  const float Z = x[pt * 3 + 2];
  half8v bf0, bf1;
#pragma unroll
  for (int j = 0; j < 8; ++j) {
    const float ha = fmaxf(fmaf(w1z[j], Z, fmaf(w1y[j], Y, fmaf(w1x[j], X, b1v[j]))), 0.f);
    const float hb = fmaxf(fmaf(w1z[8 + j], Z, fmaf(w1y[8 + j], Y, fmaf(w1x[8 + j], X, b1v[8 + j]))), 0.f);
    bf0[j] = (_Float16)ha;
    bf1[j] = (_Float16)hb;
  }

  __half* hrow = h2 + (size_t)pt * CH2;
#pragma unroll
  for (int mt = 0; mt < 4; ++mt) {
    const int mtg = mh * 4 + mt;
    float4v acc = bias[mt];
    acc = __builtin_amdgcn_mfma_f32_16x16x32_f16(afrag[mt][0], bf0, acc, 0, 0, 0);
    acc = __builtin_amdgcn_mfma_f32_16x16x32_f16(afrag[mt][1], bf1, acc, 0, 0, 0);
    const int p0 = mtg * 16 + quad * 4;
    half2v lo2, hi2;
    lo2[0] = (_Float16)fmaxf(acc[0], 0.f);
    lo2[1] = (_Float16)fmaxf(acc[1], 0.f);
    hi2[0] = (_Float16)fmaxf(acc[2], 0.f);
    hi2[1] = (_Float16)fmaxf(acc[3], 0.f);
    uint2 pk;
    pk.x = __builtin_bit_cast(unsigned, lo2);
    pk.y = __builtin_bit_cast(unsigned, hi2);
    *(uint2*)(hrow + p0) = pk;
  }
}

// ---------------------------------------------------------------------------
// Kernel 2: TWO queries per block (sA, sB = sA+1024), same batch -> shares
// candidate loads in phase 1 and amortizes phase-2/reduction latency
// exposures across 2 queries. XCD swizzle kept: b = bid & 7.
// ---------------------------------------------------------------------------
__global__ __launch_bounds__(256) void query_kernel(
    const float4v* __restrict__ xyzq,
    const __half* __restrict__ h2,
    float* __restrict__ out) {
  __shared__ int list[2][NSAMP];
  __shared__ unsigned cnt[2][2][4];   // [chunk-or-parity][query][wave]
  __shared__ uint4v partial[2][256];  // 8 KB

  const int t = threadIdx.x;
  const int wave = t >> 6;
  const int lane = t & 63;
  const int bid = blockIdx.x;          // 0 .. 8191
  const int b = bid & 7;               // batch == XCD id
  const int sA = bid >> 3;             // 0..1023
  const int sB = sA + 1024;

  const float4v* xq = xyzq + (size_t)b * NPTS;
  const float4v qvA = xq[sA];
  const float4v qvB = xq[sB];
  const float axq = qvA[0], ayq = qvA[1], azq = qvA[2], adq = qvA[3];
  const float bxq = qvB[0], byq = qvB[1], bzq = qvB[2], bdq = qvB[3];
  const double dqA = (double)axq * axq + (double)ayq * ayq + (double)azq * azq;
  const double dqB = (double)bxq * bxq + (double)byq * byq + (double)bzq * bzq;
  const unsigned long long lt = (1ull << lane) - 1ull;

  // in-radius test vs both queries (fp32 + fp64 guard band, bit-exact)
#define TEST(hit, pv, qx_, qy_, qz_, dqf_, dq_)                               \
  {                                                                           \
    const float px = pv[0], py = pv[1], pz = pv[2];                           \
    const float dot = fmaf(qz_, pz, fmaf(qy_, py, qx_ * px));                 \
    const float dist = fmaf(-2.f, dot, dqf_ + pv[3]);                         \
    if (__ballot(__builtin_fabsf(dist - 0.36f) <= 3e-5f)) {                   \
      const double dm = (double)px * px + (double)py * py + (double)pz * pz;  \
      const double dd = (double)qx_ * px + (double)qy_ * py + (double)qz_ * pz; \
      hit = !((dq_ + dm - 2.0 * dd) > 0.36);                                  \
    } else {                                                                  \
      hit = !(dist > 0.36f);                                                  \
    }                                                                         \
  }

  // ---- Phase 1a: candidates 0..511 unconditionally, shared loads ----
  const int m0 = wave * 64 + lane;
  const int m1 = 256 + m0;
  const float4v pv0 = xq[m0];
  const float4v pv1 = xq[m1];

  bool hA0, hA1, hB0, hB1;
  TEST(hA0, pv0, axq, ayq, azq, adq, dqA)
  TEST(hA1, pv1, axq, ayq, azq, adq, dqA)
  TEST(hB0, pv0, bxq, byq, bzq, bdq, dqB)
  TEST(hB1, pv1, bxq, byq, bzq, bdq, dqB)

  const unsigned long long kA0 = __ballot(hA0);
  const unsigned long long kA1 = __ballot(hA1);
  const unsigned long long kB0 = __ballot(hB0);
  const unsigned long long kB1 = __ballot(hB1);
  if (lane == 0) {
    cnt[0][0][wave] = (unsigned)__popcll(kA0);
    cnt[1][0][wave] = (unsigned)__popcll(kA1);
    cnt[0][1][wave] = (unsigned)__popcll(kB0);
    cnt[1][1][wave] = (unsigned)__popcll(kB1);
  }
  __syncthreads();

  int preA0 = 0, totA0 = 0, preA1 = 0, totA1 = 0;
  int preB0 = 0, totB0 = 0, preB1 = 0, totB1 = 0;
#pragma unroll
  for (int w = 0; w < 4; ++w) {
    const int cA0 = (int)cnt[0][0][w], cA1 = (int)cnt[1][0][w];
    const int cB0 = (int)cnt[0][1][w], cB1 = (int)cnt[1][1][w];
    if (w < wave) { preA0 += cA0; preA1 += cA1; preB0 += cB0; preB1 += cB1; }
    totA0 += cA0; totA1 += cA1; totB0 += cB0; totB1 += cB1;
  }
  preA1 += totA0;
  preB1 += totB0;
  if (hA0) { const int p = preA0 + __popcll(kA0 & lt); if (p < NSAMP) list[0][p] = m0; }
  if (hA1) { const int p = preA1 + __popcll(kA1 & lt); if (p < NSAMP) list[0][p] = m1; }
  if (hB0) { const int p = preB0 + __popcll(kB0 & lt); if (p < NSAMP) list[1][p] = m0; }
  if (hB1) { const int p = preB1 + __popcll(kB1 & lt); if (p < NSAMP) list[1][p] = m1; }
  int countA = totA0 + totA1;
  int countB = totB0 + totB1;

  // ---- Phase 1b: rare path, block-uniform branch ----
  if (countA < NSAMP || countB < NSAMP) {
    __syncthreads();   // all reads of 1a's cnt done before reuse
    int it = 0;
    for (int base2 = 512; base2 < NPTS && (countA < NSAMP || countB < NSAMP);
         base2 += 256, ++it) {
      const int m = base2 + wave * 64 + lane;
      const float4v pv = xq[m];
      bool hA, hB;
      TEST(hA, pv, axq, ayq, azq, adq, dqA)
      TEST(hB, pv, bxq, byq, bzq, bdq, dqB)
      const unsigned long long kA = __ballot(hA);
      const unsigned long long kB = __ballot(hB);
      const int par = it & 1;
      if (lane == 0) {
        cnt[par][0][wave] = (unsigned)__popcll(kA);
        cnt[par][1][wave] = (unsigned)__popcll(kB);
      }
      __syncthreads();
      int preA = countA, preB = countB, totA = 0, totB = 0;
#pragma unroll
      for (int w = 0; w < 4; ++w) {
        const int cA = (int)cnt[par][0][w];
        const int cB = (int)cnt[par][1][w];
        if (w < wave) { preA += cA; preB += cB; }
        totA += cA; totB += cB;
      }
      if (hA) { const int p = preA + __popcll(kA & lt); if (p < NSAMP) list[0][p] = m; }
      if (hB) { const int p = preB + __popcll(kB & lt); if (p < NSAMP) list[1][p] = m; }
      countA += totA;
      countB += totB;
    }
  }
#undef TEST
  if (countA > NSAMP) countA = NSAMP;
  if (countB > NSAMP) countB = NSAMP;
  __syncthreads();   // lists visible to phase 2

  // ---- Phase 2: 8 gather loads (4/query) in ONE burst ----
  const int rowsel = t >> 4;   // 0..15
  const int csl = t & 15;      // 16-B channel slice
  const unsigned long long hb =
      (unsigned long long)(h2 + (size_t)b * NPTS * CH2) + (unsigned)(csl * 16);

  unsigned long long adA[4], adB[4];
#pragma unroll
  for (int r = 0; r < 4; ++r) {
    const int ri = r * 16 + rowsel;
    const int liA = (ri < countA) ? ri : 0;   // dup of row 0 is max-neutral
    const int liB = (ri < countB) ? ri : 0;
    adA[r] = hb + (unsigned)(list[0][liA] * 256);
    adB[r] = hb + (unsigned)(list[1][liB] * 256);
  }

  uint4v a0, a1, a2, a3, b0, b1, b2, b3;
  asm volatile(
      "global_load_dwordx4 %0, %8, off\n\t"
      "global_load_dwordx4 %1, %9, off\n\t"
      "global_load_dwordx4 %2, %10, off\n\t"
      "global_load_dwordx4 %3, %11, off\n\t"
      "global_load_dwordx4 %4, %12, off\n\t"
      "global_load_dwordx4 %5, %13, off\n\t"
      "global_load_dwordx4 %6, %14, off\n\t"
      "global_load_dwordx4 %7, %15, off\n\t"
      "s_waitcnt vmcnt(0)"
      : "=&v"(a0), "=&v"(a1), "=&v"(a2), "=&v"(a3),
        "=&v"(b0), "=&v"(b1), "=&v"(b2), "=&v"(b3)
      : "v"(adA[0]), "v"(adA[1]), "v"(adA[2]), "v"(adA[3]),
        "v"(adB[0]), "v"(adB[1]), "v"(adB[2]), "v"(adB[3])
      : "memory");

  partial[0][t] = pk4max(pk4max(a0, a1), pk4max(a2, a3));
  partial[1][t] = pk4max(pk4max(b0, b1), pk4max(b2, b3));
  __syncthreads();

  // ---- Final reduction: 128 threads (64 per query), 1 dword each ----
  if (t < 128) {
    const int qi = t >> 6;      // 0 = A, 1 = B
    const int u  = t & 63;
    const int cs = u >> 2;      // 16-B slice (0..15)
    const int d  = u & 3;       // dword within slice
    const unsigned* pl = (const unsigned*)&partial[qi][0];
    unsigned m = 0;
#pragma unroll
    for (int rs = 0; rs < 16; ++rs)
      m = pmax(m, pl[(rs * 16 + cs) * 4 + d]);
    const int sq = qi ? sB : sA;
    const size_t ob = (size_t)b * CH2 * NPTS;
    out[ob + (size_t)(2 * u) * NPTS + sq]     = h2lo(m);
    out[ob + (size_t)(2 * u + 1) * NPTS + sq] = h2hi(m);
  }
}

// ---------------------------------------------------------------------------
extern "C" void kernel_launch(void* const* d_in, const int* in_sizes, int n_in,
                              void* d_out, int out_size, void* d_ws, size_t ws_size,
                              hipStream_t stream) {
  const float* x  = (const float*)d_in[0];
  const float* W1 = (const float*)d_in[1];
  const float* b1 = (const float*)d_in[2];
  const float* W2 = (const float*)d_in[3];
  const float* b2 = (const float*)d_in[4];
  float* out = (float*)d_out;

  __half*  h2   = (__half*)d_ws;                                     // 4 MB
  float4v* xyzq = (float4v*)((char*)d_ws + (size_t)4 * 1024 * 1024); // 256 KB

  mlp_kernel<<<(BATCH * NPTS) / 32, 256, 0, stream>>>(
      x, W1, b1, W2, b2, h2, xyzq);
  query_kernel<<<(BATCH * NPTS) / 2, 256, 0, stream>>>(xyzq, h2, out);
}